// Round 13
// baseline (260.589 us; speedup 1.0000x reference)
//
#include <hip/hip_runtime.h>

#define T_STEPS 2048
#define BH      128
#define KS_     128
#define VS_     64
#define KF_     32
#define VF_     64
#define LCH     32
#define NCG     32            // chunks per T-half
#define NC      (T_STEPS / LCH)
#define HALF_T  1024
#define NTHR    512
#define WSLOT   5120
#define SCLS_OFF 1310720
#define SCLF_OFF 1835008
#define RUN_OFF  2359296
#define WS_NEEDED_BYTES ((size_t)(RUN_OFF + 512) * 4)
#define SOFF    (BH*KF_*VF_)
#define YOFF    (BH*KF_*VF_ + BH*KS_*VS_)

typedef __attribute__((ext_vector_type(8))) short short8;
typedef __attribute__((ext_vector_type(16))) float f32x16;

#define MFMA32(a,b,c) __builtin_amdgcn_mfma_f32_32x32x16_bf16((a),(b),(c),0,0,0)
#define CROW(r,hi) (((r)&3) + 8*((r)>>2) + 4*(hi))

#define BARRIER_LDS() do {                                    \
    asm volatile("s_waitcnt lgkmcnt(0)" ::: "memory");        \
    __builtin_amdgcn_s_barrier();                             \
    __builtin_amdgcn_sched_barrier(0);                        \
    } while (0)

__device__ __forceinline__ unsigned short f2b(float x) {
    union { float f; unsigned u; } v; v.f = x;
    unsigned r = v.u + 0x7FFFu + ((v.u >> 16) & 1u);
    return (unsigned short)(r >> 16);
}
__device__ __forceinline__ unsigned cvtpk(float lo, float hi_) {
    unsigned r;
    asm("v_cvt_pk_bf16_f32 %0, %1, %2" : "=v"(r) : "v"(lo), "v"(hi_));
    return r;
}
__device__ __forceinline__ short8 ld8(const unsigned short* p) {
    return *(const short8*)p;
}

// ================== kernel A: fused dual-half scan, LDS-op-reduced ==================
// R12 audit: ~224 scalar u16 LDS ops/half-chunk (A-column reads, Sbs/VT scatter
// writes at 4-8-way conflicts) dominate the invariant 2.9us/chunk. This version:
// (1) k-major KT/KTf arrays -> A-fragments are conflict-free b128 row reads; the
//     1/b_s scale moves to the B side (Ws=bL*g/b*V, Wf=bLf/bf*Vf; S*=bL first).
// (2) Sbs/Sbfl publishes packed to u32 (cvt_pk) -> half the ops, lower conflicts.
// (3) VT/W staged via s-major V loads -> uint2 conflict-free writes.
__global__ __launch_bounds__(NTHR, 2)
void e90_scan(const float* __restrict__ k_fast,  const float* __restrict__ v_fast,
              const float* __restrict__ q_fast,  const float* __restrict__ decay_fast,
              const float* __restrict__ k_slow,  const float* __restrict__ v_slow,
              const float* __restrict__ q_slow,  const float* __restrict__ decay_slow,
              const float* __restrict__ slow_gate, const float* __restrict__ mix_fast,
              const float* __restrict__ mix_slow, const float* __restrict__ S_fast0,
              const float* __restrict__ S_slow0, float* __restrict__ dout,
              float* __restrict__ dws)
{
    __shared__ __align__(16) unsigned short Qs  [2][LCH][136];
    __shared__ __align__(16) unsigned short Ksl [2][LCH][136];
    __shared__ __align__(16) unsigned short Sbs [2][LCH][136];
    __shared__ __align__(16) unsigned short Psl [2][LCH][40];
    __shared__ __align__(16) unsigned short Pfl [2][LCH][40];
    __shared__ __align__(16) unsigned short Qfl [2][LCH][40];
    __shared__ __align__(16) unsigned short Kfl [2][LCH][40];
    __shared__ __align__(16) unsigned short Sbfl[2][LCH][40];
    __shared__ __align__(16) unsigned short VTs [2][2][LCH][40];
    __shared__ __align__(16) unsigned short VTf [2][2][LCH][40];
    __shared__ __align__(16) unsigned short KT  [2][KS_][40];   // k-major K~ raw
    __shared__ __align__(16) unsigned short KTf [2][KF_][40];
    __shared__ __align__(16) unsigned short Ws  [2][LCH][40];   // bL*g/b * V  [v][s]
    __shared__ __align__(16) unsigned short Wf  [2][LCH][40];   // bLf/bf * Vf [v][s]

    const int tid  = threadIdx.x;
    const int th   = tid >> 8;            // t-half
    const int gtid = tid & 255;
    const int wid4 = ((tid >> 6) + (th << 1)) & 3;
    const int lane = tid & 63;
    const int l31  = lane & 31;
    const int hi   = lane >> 5;
    const int s_   = gtid >> 3;           // 0..31 (Ksl/Qs staging row)
    const int sub  = gtid & 7;
    const int k0_  = sub * 16;
    const int j0_  = sub * 4;
    // k-major / s-major staging maps
    const int kt_k  = gtid & 127;         // KT row (k)
    const int kt_s0 = (gtid >> 7) << 4;   // KT col block (0|16)
    const int vt_v  = gtid & 31;          // VT/W row (v); also KTf row via kf_k
    const int vt_s0 = (gtid >> 5) << 2;   // 4-wide s block
    const int bid  = blockIdx.x;
    const int xcd  = bid & 7;
    const int jj   = bid >> 3;
    const int p    = xcd * 16 + (jj >> 1);
    const int vh   = jj & 1;
    const int v0   = vh * 32;
    const int slot = p * 2 + vh;
    const int tgb  = th * HALF_T;

    float* out_y = dout + YOFF;

    f32x16 St0, St1, oacc;
#pragma unroll
    for (int r = 0; r < 16; ++r) { St0[r] = 0.0f; St1[r] = 0.0f; oacc[r] = 0.0f; }
    if (th == 0) {
        if (wid4 < 2) {
#pragma unroll
            for (int r = 0; r < 16; ++r) {
                St0[r] = S_slow0[((size_t)p*KS_ + 32*(2*wid4)   + CROW(r,hi))*VS_ + v0 + l31];
                St1[r] = S_slow0[((size_t)p*KS_ + 32*(2*wid4+1) + CROW(r,hi))*VS_ + v0 + l31];
            }
        } else if (wid4 == 2) {
#pragma unroll
            for (int r = 0; r < 16; ++r)
                St0[r] = S_fast0[((size_t)p*KF_ + CROW(r,hi))*VF_ + v0 + l31];
        }
    }
    // packed u32 publish (pairs of consecutive k)
#define PUB_SLOW(TILE, ST) do {                                                \
    unsigned* prow_ = (unsigned*)&Sbs[th][l31][0];                             \
    _Pragma("unroll")                                                          \
    for (int q_ = 0; q_ < 4; ++q_) {                                           \
        int base_ = (32*(TILE) + 8*q_ + 4*hi) >> 1;                            \
        prow_[base_ + 0] = cvtpk(ST[4*q_+0], ST[4*q_+1]);                      \
        prow_[base_ + 1] = cvtpk(ST[4*q_+2], ST[4*q_+3]);                      \
    } } while (0)
#define PUB_FAST(ST) do {                                                      \
    unsigned* prow_ = (unsigned*)&Sbfl[th][l31][0];                            \
    _Pragma("unroll")                                                          \
    for (int q_ = 0; q_ < 4; ++q_) {                                           \
        int base_ = (8*q_ + 4*hi) >> 1;                                        \
        prow_[base_ + 0] = cvtpk(ST[4*q_+0], ST[4*q_+1]);                      \
        prow_[base_ + 1] = cvtpk(ST[4*q_+2], ST[4*q_+3]);                      \
    } } while (0)

    if (wid4 < 2) { PUB_SLOW(2*wid4, St0); PUB_SLOW(2*wid4+1, St1); }
    else if (wid4 == 2) { PUB_FAST(St0); }

    float4 pK0,pK1,pK2,pK3, pQ0,pQ1,pQ2,pQ3, pKf,pQf;
    float kvT[16], kfT[4], vsv[4], vfv[4];
    float pL0 = 0.f, pL1 = 0.f, pL2 = 0.f;

#define LOADCHUNK(CIDX) do {                                                    \
    int tc_ = (CIDX); if (tc_ > NCG-1) tc_ = NCG-1;                             \
    const int tb_ = tgb + tc_ * LCH;                                            \
    const float* bk_ = k_slow + ((size_t)(tb_+s_)*BH + p)*KS_ + k0_;            \
    pK0 = *(const float4*)bk_;      pK1 = *(const float4*)(bk_+4);              \
    pK2 = *(const float4*)(bk_+8);  pK3 = *(const float4*)(bk_+12);             \
    const float* bq_ = q_slow + ((size_t)(tb_+s_)*BH + p)*KS_ + k0_;            \
    pQ0 = *(const float4*)bq_;      pQ1 = *(const float4*)(bq_+4);              \
    pQ2 = *(const float4*)(bq_+8);  pQ3 = *(const float4*)(bq_+12);             \
    pKf = *(const float4*)(k_fast + ((size_t)(tb_+s_)*BH + p)*KF_ + j0_);       \
    pQf = *(const float4*)(q_fast + ((size_t)(tb_+s_)*BH + p)*KF_ + j0_);       \
    _Pragma("unroll")                                                           \
    for (int i_ = 0; i_ < 16; ++i_)                                             \
        kvT[i_] = k_slow[((size_t)(tb_+kt_s0+i_)*BH + p)*KS_ + kt_k];           \
    _Pragma("unroll")                                                           \
    for (int i_ = 0; i_ < 4; ++i_) {                                            \
        kfT[i_] = k_fast[((size_t)(tb_+vt_s0+i_)*BH + p)*KF_ + vt_v];           \
        vsv[i_] = v_slow[((size_t)(tb_+vt_s0+i_)*BH + p)*VS_ + v0 + vt_v];      \
        vfv[i_] = v_fast[((size_t)(tb_+vt_s0+i_)*BH + p)*VF_ + v0 + vt_v];      \
    }                                                                           \
    const size_t so_ = (size_t)(tb_ + l31)*BH + p;                              \
    pL0 = (hi ? decay_fast : decay_slow)[so_];                                  \
    pL1 = (hi ? mix_fast   : slow_gate )[so_];                                  \
    pL2 = hi ? 0.0f : mix_slow[so_];                                            \
    } while (0)

    LOADCHUNK(0);

    float bls = 1.f, blf = 1.f, ib = 1.f, ibf = 1.f, qsc = 0.f, qfc = 0.f;
    float runAcc = 1.0f;

    for (int c = 0; c < NCG; ++c) {
        const int cb = c & 1;
        // ================= R1 =================
        if (c > 0) {
            if (wid4 < 2) { PUB_SLOW(2*wid4, St0); PUB_SLOW(2*wid4+1, St1); }
            else if (wid4 == 2) { PUB_FAST(St0); }
            else {                          // role3: intra-out of chunk c-1 + store
                const int pb = cb ^ 1;
                f32x16 o2;
#pragma unroll
                for (int r = 0; r < 16; ++r) o2[r] = 0.0f;
                const unsigned short* ar = &Psl[th][l31][0];
                const unsigned short* br = &VTs[th][pb][l31][0];
                oacc = MFMA32(ld8(ar + 8*hi),      ld8(br + 8*hi),      oacc);
                oacc = MFMA32(ld8(ar + 16 + 8*hi), ld8(br + 16 + 8*hi), oacc);
                const unsigned short* af = &Pfl[th][l31][0];
                const unsigned short* bf = &VTf[th][pb][l31][0];
                o2 = MFMA32(ld8(af + 8*hi),      ld8(bf + 8*hi),      o2);
                o2 = MFMA32(ld8(af + 16 + 8*hi), ld8(bf + 16 + 8*hi), o2);
#pragma unroll
                for (int r = 0; r < 16; ++r) {
                    int tr = CROW(r,hi);
                    out_y[((size_t)(tgb + (c-1)*LCH + tr)*BH + p)*VF_ + v0 + l31] = oacc[r] + o2[r];
                }
            }
        }
        // ---- in-wave decay scan (+ th1 scale recording) ----
        float gob;   // per-lane g/b (slow lanes) or 1/b (fast lanes)
        {
            float a = hi ? pL0 : __builtin_fmaf(pL1, pL0, 1.0f - pL1);
            float b = a;
#pragma unroll
            for (int d = 1; d < 32; d <<= 1) {
                float y = __shfl_up(b, d, 32);
                if (l31 >= d) b *= y;
            }
            if (th == 1 && wid4 == 0) {
                float sc = (hi ? pL1 : pL2) * b * runAcc;
                float* wsp = dws + (hi ? SCLF_OFF : SCLS_OFF) + (size_t)slot*HALF_T + c*LCH + l31;
                *wsp = sc;
            }
            gob = (hi ? 1.0f : pL1) / b;
            float bs_s = __shfl(b, s_);
            float bf_s = __shfl(b, 32 + s_);
            bls = __shfl(b, 31);
            blf = __shfl(b, 63);
            float mf_s = __shfl(pL1, 32 + s_);
            float ms_s = __shfl(pL2, s_);
            ib  = 1.0f / bs_s;
            ibf = 1.0f / bf_s;
            qsc = ms_s * bs_s;
            qfc = mf_s * bf_s;
            runAcc *= (hi ? blf : bls);
        }
        // ---- stage chunk c ----
        {
            uint4 kw0, kw1, qw0, qw1;
            kw0.x = cvtpk(pK0.x*ib, pK0.y*ib);  kw0.y = cvtpk(pK0.z*ib, pK0.w*ib);
            kw0.z = cvtpk(pK1.x*ib, pK1.y*ib);  kw0.w = cvtpk(pK1.z*ib, pK1.w*ib);
            kw1.x = cvtpk(pK2.x*ib, pK2.y*ib);  kw1.y = cvtpk(pK2.z*ib, pK2.w*ib);
            kw1.z = cvtpk(pK3.x*ib, pK3.y*ib);  kw1.w = cvtpk(pK3.z*ib, pK3.w*ib);
            qw0.x = cvtpk(pQ0.x*qsc, pQ0.y*qsc); qw0.y = cvtpk(pQ0.z*qsc, pQ0.w*qsc);
            qw0.z = cvtpk(pQ1.x*qsc, pQ1.y*qsc); qw0.w = cvtpk(pQ1.z*qsc, pQ1.w*qsc);
            qw1.x = cvtpk(pQ2.x*qsc, pQ2.y*qsc); qw1.y = cvtpk(pQ2.z*qsc, pQ2.w*qsc);
            qw1.z = cvtpk(pQ3.x*qsc, pQ3.y*qsc); qw1.w = cvtpk(pQ3.z*qsc, pQ3.w*qsc);
            *(uint4*)&Ksl[th][s_][k0_]   = kw0;
            *(uint4*)&Ksl[th][s_][k0_+8] = kw1;
            *(uint4*)&Qs [th][s_][k0_]   = qw0;
            *(uint4*)&Qs [th][s_][k0_+8] = qw1;

            // per-s scales for this thread's 4 s values
            float gi0 = __shfl(pL1, vt_s0 + 0), gi1 = __shfl(pL1, vt_s0 + 1);
            float gi2 = __shfl(pL1, vt_s0 + 2), gi3 = __shfl(pL1, vt_s0 + 3);
            float ws0 = bls * __shfl(gob, vt_s0 + 0), ws1 = bls * __shfl(gob, vt_s0 + 1);
            float ws2 = bls * __shfl(gob, vt_s0 + 2), ws3 = bls * __shfl(gob, vt_s0 + 3);
            float wf0 = blf * __shfl(gob, 32 + vt_s0 + 0), wf1 = blf * __shfl(gob, 32 + vt_s0 + 1);
            float wf2 = blf * __shfl(gob, 32 + vt_s0 + 2), wf3 = blf * __shfl(gob, 32 + vt_s0 + 3);

            uint2 w2;
            w2.x = cvtpk(gi0*vsv[0], gi1*vsv[1]); w2.y = cvtpk(gi2*vsv[2], gi3*vsv[3]);
            *(uint2*)&VTs[th][cb][vt_v][vt_s0] = w2;
            w2.x = cvtpk(vfv[0], vfv[1]);          w2.y = cvtpk(vfv[2], vfv[3]);
            *(uint2*)&VTf[th][cb][vt_v][vt_s0] = w2;
            w2.x = cvtpk(ws0*vsv[0], ws1*vsv[1]);  w2.y = cvtpk(ws2*vsv[2], ws3*vsv[3]);
            *(uint2*)&Ws[th][vt_v][vt_s0] = w2;
            w2.x = cvtpk(wf0*vfv[0], wf1*vfv[1]);  w2.y = cvtpk(wf2*vfv[2], wf3*vfv[3]);
            *(uint2*)&Wf[th][vt_v][vt_s0] = w2;
            // k-major raw K (conflict-free b128 rows)
            uint4 t4;
            t4.x = cvtpk(kvT[0], kvT[1]);  t4.y = cvtpk(kvT[2], kvT[3]);
            t4.z = cvtpk(kvT[4], kvT[5]);  t4.w = cvtpk(kvT[6], kvT[7]);
            *(uint4*)&KT[th][kt_k][kt_s0] = t4;
            t4.x = cvtpk(kvT[8], kvT[9]);  t4.y = cvtpk(kvT[10], kvT[11]);
            t4.z = cvtpk(kvT[12], kvT[13]); t4.w = cvtpk(kvT[14], kvT[15]);
            *(uint4*)&KT[th][kt_k][kt_s0+8] = t4;
            w2.x = cvtpk(kfT[0], kfT[1]);  w2.y = cvtpk(kfT[2], kfT[3]);
            *(uint2*)&KTf[th][vt_v][vt_s0] = w2;

            unsigned kfp = cvtpk(pKf.x*ibf, pKf.y*ibf);
            unsigned kfp2 = cvtpk(pKf.z*ibf, pKf.w*ibf);
            *(uint2*)&Kfl[th][s_][j0_] = make_uint2(kfp, kfp2);
            unsigned qfp = cvtpk(pQf.x*qfc, pQf.y*qfc);
            unsigned qfp2 = cvtpk(pQf.z*qfc, pQf.w*qfc);
            *(uint2*)&Qfl[th][s_][j0_] = make_uint2(qfp, qfp2);
        }
        BARRIER_LDS();   // barrier A

        // ================= R2 =================
        LOADCHUNK(c + 1);

        if (wid4 < 2) {                      // two slow tiles: S = bL*S + K^T W
            const unsigned short* bw = &Ws[th][l31][0];
            short8 b1 = ld8(bw + 8*hi);
            short8 b2 = ld8(bw + 16 + 8*hi);
#pragma unroll
            for (int r = 0; r < 16; ++r) { St0[r] *= bls; St1[r] *= bls; }
            {
                const unsigned short* arow = &KT[th][32*(2*wid4) + l31][0];
                St0 = MFMA32(ld8(arow + 8*hi),      b1, St0);
                St0 = MFMA32(ld8(arow + 16 + 8*hi), b2, St0);
            }
            {
                const unsigned short* arow = &KT[th][32*(2*wid4+1) + l31][0];
                St1 = MFMA32(ld8(arow + 8*hi),      b1, St1);
                St1 = MFMA32(ld8(arow + 16 + 8*hi), b2, St1);
            }
        } else if (wid4 == 2) {              // fast state + P_fast + P_slow
            {
#pragma unroll
                for (int r = 0; r < 16; ++r) St0[r] *= blf;
                const unsigned short* arow = &KTf[th][l31][0];
                const unsigned short* bw = &Wf[th][l31][0];
                St0 = MFMA32(ld8(arow + 8*hi),      ld8(bw + 8*hi),      St0);
                St0 = MFMA32(ld8(arow + 16 + 8*hi), ld8(bw + 16 + 8*hi), St0);
            }
            {
                f32x16 p1;
#pragma unroll
                for (int r = 0; r < 16; ++r) p1[r] = 0.0f;
                const unsigned short* ar = &Qfl[th][l31][0];
                const unsigned short* br = &Kfl[th][l31][0];
                p1 = MFMA32(ld8(ar + 8*hi),      ld8(br + 8*hi),      p1);
                p1 = MFMA32(ld8(ar + 16 + 8*hi), ld8(br + 16 + 8*hi), p1);
#pragma unroll
                for (int r = 0; r < 16; ++r) {
                    int tr = CROW(r,hi);
                    Pfl[th][tr][l31] = f2b(tr >= l31 ? p1[r] : 0.0f);
                }
            }
            {
                f32x16 p1, p2;
#pragma unroll
                for (int r = 0; r < 16; ++r) { p1[r] = 0.0f; p2[r] = 0.0f; }
                const unsigned short* ar = &Qs [th][l31][0];
                const unsigned short* br = &Ksl[th][l31][0];
                const int kb = 8*hi;
#pragma unroll
                for (int st = 0; st < 8; st += 2) {
                    p1 = MFMA32(ld8(ar + kb + 16*st),     ld8(br + kb + 16*st),     p1);
                    p2 = MFMA32(ld8(ar + kb + 16*(st+1)), ld8(br + kb + 16*(st+1)), p2);
                }
#pragma unroll
                for (int r = 0; r < 16; ++r) {
                    int tr = CROW(r,hi);
                    Psl[th][tr][l31] = f2b(tr >= l31 ? p1[r] + p2[r] : 0.0f);
                }
            }
        } else {                             // role3: inter-chunk out
            f32x16 o1, o2;
#pragma unroll
            for (int r = 0; r < 16; ++r) { o1[r] = 0.0f; o2[r] = 0.0f; }
            const unsigned short* ar = &Qs [th][l31][0];
            const unsigned short* br = &Sbs[th][l31][0];
            const int kb = 8*hi;
#pragma unroll
            for (int st = 0; st < 8; st += 2) {
                o1 = MFMA32(ld8(ar + kb + 16*st),     ld8(br + kb + 16*st),     o1);
                o2 = MFMA32(ld8(ar + kb + 16*(st+1)), ld8(br + kb + 16*(st+1)), o2);
            }
            const unsigned short* af = &Qfl [th][l31][0];
            const unsigned short* bf = &Sbfl[th][l31][0];
            o1 = MFMA32(ld8(af + 8*hi),      ld8(bf + 8*hi),      o1);
            o2 = MFMA32(ld8(af + 16 + 8*hi), ld8(bf + 16 + 8*hi), o2);
#pragma unroll
            for (int r = 0; r < 16; ++r) oacc[r] = o1[r] + o2[r];
        }
        BARRIER_LDS();   // barrier B
    }

    // ---- epilogue: last-chunk intra-out + store (both halves) ----
    if (wid4 == 3) {
        const int pb = (NCG - 1) & 1;
        f32x16 o2;
#pragma unroll
        for (int r = 0; r < 16; ++r) o2[r] = 0.0f;
        const unsigned short* ar = &Psl[th][l31][0];
        const unsigned short* br = &VTs[th][pb][l31][0];
        oacc = MFMA32(ld8(ar + 8*hi),      ld8(br + 8*hi),      oacc);
        oacc = MFMA32(ld8(ar + 16 + 8*hi), ld8(br + 16 + 8*hi), oacc);
        const unsigned short* af = &Pfl[th][l31][0];
        const unsigned short* bf = &VTf[th][pb][l31][0];
        o2 = MFMA32(ld8(af + 8*hi),      ld8(bf + 8*hi),      o2);
        o2 = MFMA32(ld8(af + 16 + 8*hi), ld8(bf + 16 + 8*hi), o2);
#pragma unroll
        for (int r = 0; r < 16; ++r) {
            int tr = CROW(r,hi);
            out_y[((size_t)(tgb + (NCG-1)*LCH + tr)*BH + p)*VF_ + v0 + l31] = oacc[r] + o2[r];
        }
    }

    // ---- finals ----
    if (th == 0) {
        if (wid4 < 2) {
#pragma unroll
            for (int r = 0; r < 16; ++r) {
                int cr = CROW(r,hi);
                dout[SOFF + ((size_t)p*KS_ + 32*(2*wid4)   + cr)*VS_ + v0 + l31] = St0[r];
                dout[SOFF + ((size_t)p*KS_ + 32*(2*wid4+1) + cr)*VS_ + v0 + l31] = St1[r];
            }
        } else if (wid4 == 2) {
#pragma unroll
            for (int r = 0; r < 16; ++r)
                dout[((size_t)p*KF_ + CROW(r,hi))*VF_ + v0 + l31] = St0[r];
        }
    } else {
        if (wid4 < 2) {
#pragma unroll
            for (int r = 0; r < 16; ++r) {
                int cr = CROW(r,hi);
                dws[(size_t)slot*WSLOT + (32*(2*wid4)   + cr)*32 + l31] = St0[r];
                dws[(size_t)slot*WSLOT + (32*(2*wid4+1) + cr)*32 + l31] = St1[r];
            }
        } else if (wid4 == 2) {
#pragma unroll
            for (int r = 0; r < 16; ++r)
                dws[(size_t)slot*WSLOT + (128 + CROW(r,hi))*32 + l31] = St0[r];
        }
        if (wid4 == 0 && lane == 0)  dws[RUN_OFF + slot*2 + 0] = runAcc;
        if (wid4 == 0 && lane == 32) dws[RUN_OFF + slot*2 + 1] = runAcc;
    }
#undef LOADCHUNK
#undef PUB_SLOW
#undef PUB_FAST
}

// ====================== kernel B: inter-half fix (validated R8-R12) ======================
__global__ __launch_bounds__(NTHR, 2)
void e90_fix(const float* __restrict__ q_fast, const float* __restrict__ q_slow,
             const float* __restrict__ dws, float* __restrict__ dout)
{
    __shared__ __align__(16) unsigned short SbS[32][136];
    __shared__ __align__(16) unsigned short SbF[32][40];

    const int tid  = threadIdx.x;
    const int bid  = blockIdx.x;
    const int xcd  = bid & 7;
    const int jj   = bid >> 3;
    const int p    = xcd * 16 + (jj >> 1);
    const int vh   = jj & 1;
    const int v0   = vh * 32;
    const int slot = p * 2 + vh;
    const int lane = tid & 63;
    const int w8   = tid >> 6;
    const int l31  = lane & 31;
    const int hi   = lane >> 5;

    float* out_y = dout + YOFF;

    for (int i = tid; i < 128 * 32; i += NTHR) {
        int k = i >> 5, v = i & 31;
        SbS[v][k] = f2b(dout[SOFF + ((size_t)p*KS_ + k)*VS_ + v0 + v]);
    }
    for (int i = tid; i < 32 * 32; i += NTHR) {
        int k = i >> 5, v = i & 31;
        SbF[v][k] = f2b(dout[((size_t)p*KF_ + k)*VF_ + v0 + v]);
    }
    __syncthreads();

    {
        const float runS = dws[RUN_OFF + slot*2 + 0];
        const float runF = dws[RUN_OFF + slot*2 + 1];
        for (int i = tid; i < WSLOT; i += NTHR) {
            int k = i >> 5, v = i & 31;
            float st = dws[(size_t)slot*WSLOT + i];
            if (k < 128) {
                size_t o = SOFF + ((size_t)p*KS_ + k)*VS_ + v0 + v;
                dout[o] = runS * dout[o] + st;
            } else {
                size_t o = ((size_t)p*KF_ + (k - 128))*VF_ + v0 + v;
                dout[o] = runF * dout[o] + st;
            }
        }
    }

#pragma unroll 1
    for (int j = 0; j < 4; ++j) {
        const int cc = w8 * 4 + j;
        const int t0 = HALF_T + cc * LCH;
        const float sS = dws[SCLS_OFF + (size_t)slot*HALF_T + cc*LCH + l31];
        const float sF = dws[SCLF_OFF + (size_t)slot*HALF_T + cc*LCH + l31];
        const size_t so = (size_t)(t0 + l31) * BH + p;
        f32x16 c1, c2;
#pragma unroll
        for (int r = 0; r < 16; ++r) { c1[r] = 0.0f; c2[r] = 0.0f; }
#pragma unroll
        for (int st = 0; st < 8; ++st) {
            const float* qp = q_slow + so*KS_ + 16*st + 8*hi;
            float4 x = *(const float4*)qp;
            float4 y = *(const float4*)(qp + 4);
            union { unsigned u[4]; short8 s; } fr;
            fr.u[0] = cvtpk(x.x*sS, x.y*sS);
            fr.u[1] = cvtpk(x.z*sS, x.w*sS);
            fr.u[2] = cvtpk(y.x*sS, y.y*sS);
            fr.u[3] = cvtpk(y.z*sS, y.w*sS);
            if (st & 1) c2 = MFMA32(fr.s, ld8(&SbS[l31][16*st + 8*hi]), c2);
            else        c1 = MFMA32(fr.s, ld8(&SbS[l31][16*st + 8*hi]), c1);
        }
#pragma unroll
        for (int st = 0; st < 2; ++st) {
            const float* qp = q_fast + so*KF_ + 16*st + 8*hi;
            float4 x = *(const float4*)qp;
            float4 y = *(const float4*)(qp + 4);
            union { unsigned u[4]; short8 s; } fr;
            fr.u[0] = cvtpk(x.x*sF, x.y*sF);
            fr.u[1] = cvtpk(x.z*sF, x.w*sF);
            fr.u[2] = cvtpk(y.x*sF, y.y*sF);
            fr.u[3] = cvtpk(y.z*sF, y.w*sF);
            if (st & 1) c2 = MFMA32(fr.s, ld8(&SbF[l31][16*st + 8*hi]), c2);
            else        c1 = MFMA32(fr.s, ld8(&SbF[l31][16*st + 8*hi]), c1);
        }
#pragma unroll
        for (int r = 0; r < 16; ++r) {
            int tr = CROW(r,hi);
            size_t o = ((size_t)(t0 + tr)*BH + p)*VF_ + v0 + l31;
            out_y[o] += c1[r] + c2[r];
        }
    }
}

// ==================== fallback: R6 single-kernel (186us, proven) ====================
__global__ __launch_bounds__(NTHR, 2)
void e90_mono(const float* __restrict__ k_fast,  const float* __restrict__ v_fast,
              const float* __restrict__ q_fast,  const float* __restrict__ decay_fast,
              const float* __restrict__ k_slow,  const float* __restrict__ v_slow,
              const float* __restrict__ q_slow,  const float* __restrict__ decay_slow,
              const float* __restrict__ slow_gate, const float* __restrict__ mix_fast,
              const float* __restrict__ mix_slow, const float* __restrict__ S_fast0,
              const float* __restrict__ S_slow0, float* __restrict__ dout)
{
    __shared__ __align__(16) unsigned short Qs  [2][LCH][136];
    __shared__ __align__(16) unsigned short Ksl [2][LCH][136];
    __shared__ __align__(16) unsigned short Sbs [2][LCH][136];
    __shared__ __align__(16) unsigned short Psl [2][LCH][40];
    __shared__ __align__(16) unsigned short Pfl [2][LCH][40];
    __shared__ __align__(16) unsigned short Qfl [2][LCH][40];
    __shared__ __align__(16) unsigned short Kfl [2][LCH][40];
    __shared__ __align__(16) unsigned short Sbfl[2][LCH][40];
    __shared__ __align__(16) unsigned short VTs [3][LCH][40];
    __shared__ __align__(16) unsigned short VTf [3][LCH][40];

    const int tid  = threadIdx.x;
    const int bid  = blockIdx.x;
    const int xcd  = bid & 7;
    const int jj   = bid >> 3;
    const int p    = xcd * 16 + (jj >> 1);
    const int v0   = (jj & 1) * 32;
    const int lane = tid & 63;
    const int wid  = tid >> 6;
    const int l31  = lane & 31;
    const int hi   = lane >> 5;
    const int s_   = tid >> 4;
    const int j0_  = (tid & 15) * 2;
    const int k0_  = (tid & 15) * 8;

    float* out_y = dout + YOFF;

    f32x16 Sst, oacc;
#pragma unroll
    for (int r = 0; r < 16; ++r) { Sst[r] = 0.0f; oacc[r] = 0.0f; }
    if (wid < 4) {
#pragma unroll
        for (int r = 0; r < 16; ++r)
            Sst[r] = S_slow0[((size_t)p*KS_ + 32*wid + CROW(r,hi))*VS_ + v0 + l31];
#pragma unroll
        for (int r = 0; r < 16; ++r) Sbs[0][l31][32*wid + CROW(r,hi)] = f2b(Sst[r]);
    } else if (wid == 4) {
#pragma unroll
        for (int r = 0; r < 16; ++r)
            Sst[r] = S_fast0[((size_t)p*KF_ + CROW(r,hi))*VF_ + v0 + l31];
#pragma unroll
        for (int r = 0; r < 16; ++r) Sbfl[0][l31][CROW(r,hi)] = f2b(Sst[r]);
    }

    float4 pKs0, pKs1, pQs0, pQs1;
    float2 pVs, pVf, pKf, pQf;
    float pL0 = 0.f, pL1 = 0.f, pL2 = 0.f;
    float bls = 1.f, blf = 1.f, ib = 1.f, ibf = 1.f, qsc = 0.f, qfc = 0.f, g_s = 0.f;

#define LOADVEC(CIDX) do {                                                     \
    int tc_ = (CIDX); if (tc_ > NC-1) tc_ = NC-1;                              \
    const int tb_ = tc_ * LCH;                                                 \
    const float* bk_ = k_slow + ((size_t)(tb_+s_)*BH + p)*KS_ + k0_;           \
    pKs0 = *(const float4*)bk_;  pKs1 = *(const float4*)(bk_+4);               \
    const float* bq_ = q_slow + ((size_t)(tb_+s_)*BH + p)*KS_ + k0_;           \
    pQs0 = *(const float4*)bq_;  pQs1 = *(const float4*)(bq_+4);               \
    pVs = *(const float2*)(v_slow + ((size_t)(tb_+s_)*BH + p)*VS_ + v0 + j0_); \
    pVf = *(const float2*)(v_fast + ((size_t)(tb_+s_)*BH + p)*VF_ + v0 + j0_); \
    pKf = *(const float2*)(k_fast + ((size_t)(tb_+s_)*BH + p)*KF_ + j0_);      \
    pQf = *(const float2*)(q_fast + ((size_t)(tb_+s_)*BH + p)*KF_ + j0_);      \
    } while (0)

#define LOADSCL(CIDX) do {                                                     \
    int tc_ = (CIDX); if (tc_ > NC-1) tc_ = NC-1;                              \
    const size_t so_ = (size_t)(tc_*LCH + l31)*BH + p;                         \
    pL0 = (hi ? decay_fast : decay_slow)[so_];                                 \
    pL1 = (hi ? mix_fast   : slow_gate )[so_];                                 \
    pL2 = hi ? 0.0f : mix_slow[so_];                                           \
    } while (0)

#define SCAN() do {                                                            \
    float a_ = hi ? pL0 : __builtin_fmaf(pL1, pL0, 1.0f - pL1);                \
    float b_ = a_;                                                             \
    _Pragma("unroll")                                                          \
    for (int d = 1; d < 32; d <<= 1) {                                         \
        float y_ = __shfl_up(b_, d, 32);                                       \
        if (l31 >= d) b_ *= y_;                                                \
    }                                                                          \
    float bs_s = __shfl(b_, s_);                                               \
    float bf_s = __shfl(b_, 32 + s_);                                          \
    bls = __shfl(b_, 31);                                                      \
    blf = __shfl(b_, 63);                                                      \
    g_s = __shfl(pL1, s_);                                                     \
    float mf_s = __shfl(pL1, 32 + s_);                                         \
    float ms_s = __shfl(pL2, s_);                                              \
    ib  = 1.0f / bs_s;                                                         \
    ibf = 1.0f / bf_s;                                                         \
    qsc = ms_s * bs_s;                                                         \
    qfc = mf_s * bf_s;                                                         \
    } while (0)

#define STAGE(J2, J3) do {                                                     \
    uint4 kw, qw;                                                              \
    kw.x = cvtpk(pKs0.x*ib, pKs0.y*ib);  kw.y = cvtpk(pKs0.z*ib, pKs0.w*ib);   \
    kw.z = cvtpk(pKs1.x*ib, pKs1.y*ib);  kw.w = cvtpk(pKs1.z*ib, pKs1.w*ib);   \
    qw.x = cvtpk(pQs0.x*qsc, pQs0.y*qsc); qw.y = cvtpk(pQs0.z*qsc, pQs0.w*qsc);\
    qw.z = cvtpk(pQs1.x*qsc, pQs1.y*qsc); qw.w = cvtpk(pQs1.z*qsc, pQs1.w*qsc);\
    *(uint4*)&Ksl[J2][s_][k0_] = kw;                                           \
    *(uint4*)&Qs [J2][s_][k0_] = qw;                                           \
    float vt0 = g_s*pVs.x, vt1 = g_s*pVs.y;                                    \
    VTs[J3][j0_  ][s_] = f2b(vt0);                                             \
    VTs[J3][j0_+1][s_] = f2b(vt1);                                             \
    VTf[J3][j0_  ][s_] = f2b(pVf.x);                                           \
    VTf[J3][j0_+1][s_] = f2b(pVf.y);                                           \
    unsigned kfp = cvtpk(pKf.x*ibf, pKf.y*ibf);                                \
    *(unsigned*)&Kfl[J2][s_][j0_] = kfp;                                       \
    unsigned qfp = cvtpk(pQf.x*qfc, pQf.y*qfc);                                \
    *(unsigned*)&Qfl[J2][s_][j0_] = qfp;                                       \
    } while (0)

#define YSTORE(CP) do {                                                        \
    const int p2_ = (CP) & 1, p3_ = (CP) % 3;                                  \
    f32x16 o2;                                                                 \
    _Pragma("unroll")                                                          \
    for (int r = 0; r < 16; ++r) o2[r] = 0.0f;                                 \
    const unsigned short* ar = &Psl[p2_][l31][0];                              \
    const unsigned short* br = &VTs[p3_][l31][0];                              \
    oacc = MFMA32(ld8(ar + 8*hi),      ld8(br + 8*hi),      oacc);             \
    oacc = MFMA32(ld8(ar + 16 + 8*hi), ld8(br + 16 + 8*hi), oacc);             \
    const unsigned short* af = &Pfl[p2_][l31][0];                              \
    const unsigned short* bf = &VTf[p3_][l31][0];                              \
    o2 = MFMA32(ld8(af + 8*hi),      ld8(bf + 8*hi),      o2);                 \
    o2 = MFMA32(ld8(af + 16 + 8*hi), ld8(bf + 16 + 8*hi), o2);                 \
    _Pragma("unroll")                                                          \
    for (int r = 0; r < 16; ++r) {                                             \
        int tr = CROW(r,hi);                                                   \
        out_y[((size_t)((CP)*LCH + tr)*BH + p)*VF_ + v0 + l31] = oacc[r] + o2[r]; \
    }                                                                          \
    } while (0)

    LOADVEC(0);
    LOADSCL(0);
    SCAN();
    LOADSCL(1);
    STAGE(0, 0);
    __syncthreads();

    for (int c = 0; c < NC; ++c) {
        const int i2 = c & 1;
        const int i3 = c % 3;
        LOADVEC(c + 1);

        if (wid < 4) {
            short8 a1, a2;
#pragma unroll
            for (int e = 0; e < 8; ++e) {
                a1[e] = (short)Ksl[i2][8*hi + e][32*wid + l31];
                a2[e] = (short)Ksl[i2][16 + 8*hi + e][32*wid + l31];
            }
            const unsigned short* br = &VTs[i3][l31][0];
            Sst = MFMA32(a1, ld8(br + 8*hi),      Sst);
            Sst = MFMA32(a2, ld8(br + 16 + 8*hi), Sst);
#pragma unroll
            for (int r = 0; r < 16; ++r) Sst[r] *= bls;
        } else if (wid == 4) {
            short8 a1, a2;
#pragma unroll
            for (int e = 0; e < 8; ++e) {
                a1[e] = (short)Kfl[i2][8*hi + e][l31];
                a2[e] = (short)Kfl[i2][16 + 8*hi + e][l31];
            }
            const unsigned short* br = &VTf[i3][l31][0];
            Sst = MFMA32(a1, ld8(br + 8*hi),      Sst);
            Sst = MFMA32(a2, ld8(br + 16 + 8*hi), Sst);
#pragma unroll
            for (int r = 0; r < 16; ++r) Sst[r] *= blf;
        } else if (wid == 5) {
            f32x16 p1, p2;
#pragma unroll
            for (int r = 0; r < 16; ++r) { p1[r] = 0.0f; p2[r] = 0.0f; }
            const unsigned short* ar = &Qs [i2][l31][0];
            const unsigned short* br = &Ksl[i2][l31][0];
            const int kb = 8*hi;
#pragma unroll
            for (int st = 0; st < 8; st += 2) {
                p1 = MFMA32(ld8(ar + kb + 16*st),     ld8(br + kb + 16*st),     p1);
                p2 = MFMA32(ld8(ar + kb + 16*(st+1)), ld8(br + kb + 16*(st+1)), p2);
            }
#pragma unroll
            for (int r = 0; r < 16; ++r) {
                int tr = CROW(r,hi);
                Psl[i2][tr][l31] = f2b(tr >= l31 ? p1[r] + p2[r] : 0.0f);
            }
        } else if (wid == 6) {
            f32x16 p1;
#pragma unroll
            for (int r = 0; r < 16; ++r) p1[r] = 0.0f;
            const unsigned short* ar = &Qfl[i2][l31][0];
            const unsigned short* br = &Kfl[i2][l31][0];
            p1 = MFMA32(ld8(ar + 8*hi),      ld8(br + 8*hi),      p1);
            p1 = MFMA32(ld8(ar + 16 + 8*hi), ld8(br + 16 + 8*hi), p1);
#pragma unroll
            for (int r = 0; r < 16; ++r) {
                int tr = CROW(r,hi);
                Pfl[i2][tr][l31] = f2b(tr >= l31 ? p1[r] : 0.0f);
            }
        } else {
            if (c > 0) YSTORE(c - 1);
            f32x16 o1, o2;
#pragma unroll
            for (int r = 0; r < 16; ++r) { o1[r] = 0.0f; o2[r] = 0.0f; }
            const unsigned short* ar = &Qs [i2][l31][0];
            const unsigned short* br = &Sbs[i2][l31][0];
            const int kb = 8*hi;
#pragma unroll
            for (int st = 0; st < 8; st += 2) {
                o1 = MFMA32(ld8(ar + kb + 16*st),     ld8(br + kb + 16*st),     o1);
                o2 = MFMA32(ld8(ar + kb + 16*(st+1)), ld8(br + kb + 16*(st+1)), o2);
            }
            const unsigned short* af = &Qfl [i2][l31][0];
            const unsigned short* bf = &Sbfl[i2][l31][0];
            o1 = MFMA32(ld8(af + 8*hi),      ld8(bf + 8*hi),      o1);
            o2 = MFMA32(ld8(af + 16 + 8*hi), ld8(bf + 16 + 8*hi), o2);
#pragma unroll
            for (int r = 0; r < 16; ++r) oacc[r] = o1[r] + o2[r];
        }

        SCAN();
        LOADSCL(c + 2);

        if (c < NC - 1) {
            const int j2 = (c + 1) & 1;
            const int j3 = (c + 1) % 3;
            if (wid < 4) {
#pragma unroll
                for (int r = 0; r < 16; ++r) Sbs[j2][l31][32*wid + CROW(r,hi)] = f2b(Sst[r]);
            } else if (wid == 4) {
#pragma unroll
                for (int r = 0; r < 16; ++r) Sbfl[j2][l31][CROW(r,hi)] = f2b(Sst[r]);
            }
            STAGE(j2, j3);
        }
        __syncthreads();
    }

    if (wid == 7) {
        YSTORE(NC - 1);
    }
    if (wid < 4) {
#pragma unroll
        for (int r = 0; r < 16; ++r)
            dout[SOFF + ((size_t)p*KS_ + 32*wid + CROW(r,hi))*VS_ + v0 + l31] = Sst[r];
    } else if (wid == 4) {
#pragma unroll
        for (int r = 0; r < 16; ++r)
            dout[((size_t)p*KF_ + CROW(r,hi))*VF_ + v0 + l31] = Sst[r];
    }
#undef LOADVEC
#undef LOADSCL
#undef SCAN
#undef STAGE
#undef YSTORE
}

extern "C" void kernel_launch(void* const* d_in, const int* in_sizes, int n_in,
                              void* d_out, int out_size, void* d_ws, size_t ws_size,
                              hipStream_t stream)
{
    const float* k_fast     = (const float*)d_in[0];
    const float* v_fast     = (const float*)d_in[1];
    const float* q_fast     = (const float*)d_in[2];
    const float* decay_fast = (const float*)d_in[3];
    const float* k_slow     = (const float*)d_in[4];
    const float* v_slow     = (const float*)d_in[5];
    const float* q_slow     = (const float*)d_in[6];
    const float* decay_slow = (const float*)d_in[7];
    const float* slow_gate  = (const float*)d_in[8];
    const float* mix_fast   = (const float*)d_in[9];
    const float* mix_slow   = (const float*)d_in[10];
    const float* S_fast0    = (const float*)d_in[11];
    const float* S_slow0    = (const float*)d_in[12];
    float* dout = (float*)d_out;
    float* dws  = (float*)d_ws;

    if (ws_size >= WS_NEEDED_BYTES) {
        e90_scan<<<dim3(256), dim3(NTHR), 0, stream>>>(
            k_fast, v_fast, q_fast, decay_fast,
            k_slow, v_slow, q_slow, decay_slow,
            slow_gate, mix_fast, mix_slow, S_fast0, S_slow0, dout, dws);
        e90_fix<<<dim3(256), dim3(NTHR), 0, stream>>>(q_fast, q_slow, dws, dout);
    } else {
        e90_mono<<<dim3(256), dim3(NTHR), 0, stream>>>(
            k_fast, v_fast, q_fast, decay_fast,
            k_slow, v_slow, q_slow, decay_slow,
            slow_gate, mix_fast, mix_slow, S_fast0, S_slow0, dout);
    }
}

// Round 14
// 187.150 us; speedup vs baseline: 1.3924x; 1.3924x over previous
//
#include <hip/hip_runtime.h>

#define T_STEPS 2048
#define BH      128
#define KS_     128
#define VS_     64
#define KF_     32
#define VF_     64
#define LCH     32
#define NC      (T_STEPS / LCH)
#define NTHR    512

typedef __attribute__((ext_vector_type(8))) short short8;
typedef __attribute__((ext_vector_type(16))) float f32x16;

#define MFMA32(a,b,c) __builtin_amdgcn_mfma_f32_32x32x16_bf16((a),(b),(c),0,0,0)
#define CROW(r,hi) (((r)&3) + 8*((r)>>2) + 4*(hi))

__device__ __forceinline__ unsigned short f2b(float x) {
    union { float f; unsigned u; } v; v.f = x;
    unsigned r = v.u + 0x7FFFu + ((v.u >> 16) & 1u);
    return (unsigned short)(r >> 16);
}
__device__ __forceinline__ unsigned cvtpk(float lo, float hi_) {
    unsigned r;
    asm("v_cvt_pk_bf16_f32 %0, %1, %2" : "=v"(r) : "v"(lo), "v"(hi_));
    return r;
}
__device__ __forceinline__ short8 ld8(const unsigned short* p) {
    return *(const short8*)p;
}

// R6 single-kernel full-T scan — best measured configuration (186.7 us).
// One barrier per chunk: dbuf chunk arrays ([2]), VT 3-buffered, y-store in
// the MFMA phase, decay-scan hoisted one chunk early (depth-2 scalar prefetch).
__global__ __launch_bounds__(NTHR, 2)
void e90_mfma(const float* __restrict__ k_fast,  const float* __restrict__ v_fast,
              const float* __restrict__ q_fast,  const float* __restrict__ decay_fast,
              const float* __restrict__ k_slow,  const float* __restrict__ v_slow,
              const float* __restrict__ q_slow,  const float* __restrict__ decay_slow,
              const float* __restrict__ slow_gate, const float* __restrict__ mix_fast,
              const float* __restrict__ mix_slow, const float* __restrict__ S_fast0,
              const float* __restrict__ S_slow0, float* __restrict__ dout)
{
    __shared__ __align__(16) unsigned short Qs  [2][LCH][136];
    __shared__ __align__(16) unsigned short Ksl [2][LCH][136];
    __shared__ __align__(16) unsigned short Sbs [2][LCH][136];
    __shared__ __align__(16) unsigned short Psl [2][LCH][40];
    __shared__ __align__(16) unsigned short Pfl [2][LCH][40];
    __shared__ __align__(16) unsigned short Qfl [2][LCH][40];
    __shared__ __align__(16) unsigned short Kfl [2][LCH][40];
    __shared__ __align__(16) unsigned short Sbfl[2][LCH][40];
    __shared__ __align__(16) unsigned short VTs [3][LCH][40];
    __shared__ __align__(16) unsigned short VTf [3][LCH][40];

    const int tid  = threadIdx.x;
    const int bid  = blockIdx.x;
    const int xcd  = bid & 7;
    const int jj   = bid >> 3;
    const int p    = xcd * 16 + (jj >> 1);   // (b*H+h) 0..127
    const int v0   = (jj & 1) * 32;          // v-half
    const int lane = tid & 63;
    const int wid  = tid >> 6;
    const int l31  = lane & 31;
    const int hi   = lane >> 5;
    const int s_   = tid >> 4;               // 0..31
    const int j0_  = (tid & 15) * 2;
    const int k0_  = (tid & 15) * 8;

    float* out_y = dout + BH*KF_*VF_ + BH*KS_*VS_;

    // ---- state init + initial publish into buffer 0 ----
    f32x16 Sst, oacc;
#pragma unroll
    for (int r = 0; r < 16; ++r) { Sst[r] = 0.0f; oacc[r] = 0.0f; }
    if (wid < 4) {
#pragma unroll
        for (int r = 0; r < 16; ++r)
            Sst[r] = S_slow0[((size_t)p*KS_ + 32*wid + CROW(r,hi))*VS_ + v0 + l31];
#pragma unroll
        for (int r = 0; r < 16; ++r) Sbs[0][l31][32*wid + CROW(r,hi)] = f2b(Sst[r]);
    } else if (wid == 4) {
#pragma unroll
        for (int r = 0; r < 16; ++r)
            Sst[r] = S_fast0[((size_t)p*KF_ + CROW(r,hi))*VF_ + v0 + l31];
#pragma unroll
        for (int r = 0; r < 16; ++r) Sbfl[0][l31][CROW(r,hi)] = f2b(Sst[r]);
    }

    // ---- prefetch regs ----
    float4 pKs0, pKs1, pQs0, pQs1;
    float2 pVs, pVf, pKf, pQf;
    float pL0 = 0.f, pL1 = 0.f, pL2 = 0.f;
    float bls = 1.f, blf = 1.f, ib = 1.f, ibf = 1.f, qsc = 0.f, qfc = 0.f, g_s = 0.f;

#define LOADVEC(CIDX) do {                                                     \
    int tc_ = (CIDX); if (tc_ > NC-1) tc_ = NC-1;                              \
    const int tb_ = tc_ * LCH;                                                 \
    const float* bk_ = k_slow + ((size_t)(tb_+s_)*BH + p)*KS_ + k0_;           \
    pKs0 = *(const float4*)bk_;  pKs1 = *(const float4*)(bk_+4);               \
    const float* bq_ = q_slow + ((size_t)(tb_+s_)*BH + p)*KS_ + k0_;           \
    pQs0 = *(const float4*)bq_;  pQs1 = *(const float4*)(bq_+4);               \
    pVs = *(const float2*)(v_slow + ((size_t)(tb_+s_)*BH + p)*VS_ + v0 + j0_); \
    pVf = *(const float2*)(v_fast + ((size_t)(tb_+s_)*BH + p)*VF_ + v0 + j0_); \
    pKf = *(const float2*)(k_fast + ((size_t)(tb_+s_)*BH + p)*KF_ + j0_);      \
    pQf = *(const float2*)(q_fast + ((size_t)(tb_+s_)*BH + p)*KF_ + j0_);      \
    } while (0)

#define LOADSCL(CIDX) do {                                                     \
    int tc_ = (CIDX); if (tc_ > NC-1) tc_ = NC-1;                              \
    const size_t so_ = (size_t)(tc_*LCH + l31)*BH + p;                         \
    pL0 = (hi ? decay_fast : decay_slow)[so_];                                 \
    pL1 = (hi ? mix_fast   : slow_gate )[so_];                                 \
    pL2 = hi ? 0.0f : mix_slow[so_];                                           \
    } while (0)

#define SCAN() do {                                                            \
    float a_ = hi ? pL0 : __builtin_fmaf(pL1, pL0, 1.0f - pL1);                \
    float b_ = a_;                                                             \
    _Pragma("unroll")                                                          \
    for (int d = 1; d < 32; d <<= 1) {                                         \
        float y_ = __shfl_up(b_, d, 32);                                       \
        if (l31 >= d) b_ *= y_;                                                \
    }                                                                          \
    float bs_s = __shfl(b_, s_);                                               \
    float bf_s = __shfl(b_, 32 + s_);                                          \
    bls = __shfl(b_, 31);                                                      \
    blf = __shfl(b_, 63);                                                      \
    g_s = __shfl(pL1, s_);                                                     \
    float mf_s = __shfl(pL1, 32 + s_);                                         \
    float ms_s = __shfl(pL2, s_);                                              \
    ib  = 1.0f / bs_s;                                                         \
    ibf = 1.0f / bf_s;                                                         \
    qsc = ms_s * bs_s;                                                         \
    qfc = mf_s * bf_s;                                                         \
    } while (0)

#define STAGE(J2, J3) do {                                                     \
    uint4 kw, qw;                                                              \
    kw.x = cvtpk(pKs0.x*ib, pKs0.y*ib);  kw.y = cvtpk(pKs0.z*ib, pKs0.w*ib);   \
    kw.z = cvtpk(pKs1.x*ib, pKs1.y*ib);  kw.w = cvtpk(pKs1.z*ib, pKs1.w*ib);   \
    qw.x = cvtpk(pQs0.x*qsc, pQs0.y*qsc); qw.y = cvtpk(pQs0.z*qsc, pQs0.w*qsc);\
    qw.z = cvtpk(pQs1.x*qsc, pQs1.y*qsc); qw.w = cvtpk(pQs1.z*qsc, pQs1.w*qsc);\
    *(uint4*)&Ksl[J2][s_][k0_] = kw;                                           \
    *(uint4*)&Qs [J2][s_][k0_] = qw;                                           \
    float vt0 = g_s*pVs.x, vt1 = g_s*pVs.y;                                    \
    VTs[J3][j0_  ][s_] = f2b(vt0);                                             \
    VTs[J3][j0_+1][s_] = f2b(vt1);                                             \
    VTf[J3][j0_  ][s_] = f2b(pVf.x);                                           \
    VTf[J3][j0_+1][s_] = f2b(pVf.y);                                           \
    unsigned kfp = cvtpk(pKf.x*ibf, pKf.y*ibf);                                \
    *(unsigned*)&Kfl[J2][s_][j0_] = kfp;                                       \
    unsigned qfp = cvtpk(pQf.x*qfc, pQf.y*qfc);                                \
    *(unsigned*)&Qfl[J2][s_][j0_] = qfp;                                       \
    } while (0)

#define YSTORE(CP) do {                                                        \
    const int p2_ = (CP) & 1, p3_ = (CP) % 3;                                  \
    f32x16 o2;                                                                 \
    _Pragma("unroll")                                                          \
    for (int r = 0; r < 16; ++r) o2[r] = 0.0f;                                 \
    const unsigned short* ar = &Psl[p2_][l31][0];                              \
    const unsigned short* br = &VTs[p3_][l31][0];                              \
    oacc = MFMA32(ld8(ar + 8*hi),      ld8(br + 8*hi),      oacc);             \
    oacc = MFMA32(ld8(ar + 16 + 8*hi), ld8(br + 16 + 8*hi), oacc);             \
    const unsigned short* af = &Pfl[p2_][l31][0];                              \
    const unsigned short* bf = &VTf[p3_][l31][0];                              \
    o2 = MFMA32(ld8(af + 8*hi),      ld8(bf + 8*hi),      o2);                 \
    o2 = MFMA32(ld8(af + 16 + 8*hi), ld8(bf + 16 + 8*hi), o2);                 \
    _Pragma("unroll")                                                          \
    for (int r = 0; r < 16; ++r) {                                             \
        int tr = CROW(r,hi);                                                   \
        out_y[((size_t)((CP)*LCH + tr)*BH + p)*VF_ + v0 + l31] = oacc[r] + o2[r]; \
    }                                                                          \
    } while (0)

    // ---- prologue ----
    LOADVEC(0);
    LOADSCL(0);
    SCAN();          // res for chunk 0
    LOADSCL(1);
    STAGE(0, 0);
    __syncthreads();

    for (int c = 0; c < NC; ++c) {
        const int i2 = c & 1;
        const int i3 = c % 3;

        LOADVEC(c + 1);

        // ================= MFMA phase (chunk c) =================
        if (wid < 4) {                       // slow state: S = bL*(S + K~^T Vg)
            short8 a1, a2;
#pragma unroll
            for (int e = 0; e < 8; ++e) {
                a1[e] = (short)Ksl[i2][8*hi + e][32*wid + l31];
                a2[e] = (short)Ksl[i2][16 + 8*hi + e][32*wid + l31];
            }
            const unsigned short* br = &VTs[i3][l31][0];
            Sst = MFMA32(a1, ld8(br + 8*hi),      Sst);
            Sst = MFMA32(a2, ld8(br + 16 + 8*hi), Sst);
#pragma unroll
            for (int r = 0; r < 16; ++r) Sst[r] *= bls;
        } else if (wid == 4) {               // fast state
            short8 a1, a2;
#pragma unroll
            for (int e = 0; e < 8; ++e) {
                a1[e] = (short)Kfl[i2][8*hi + e][l31];
                a2[e] = (short)Kfl[i2][16 + 8*hi + e][l31];
            }
            const unsigned short* br = &VTf[i3][l31][0];
            Sst = MFMA32(a1, ld8(br + 8*hi),      Sst);
            Sst = MFMA32(a2, ld8(br + 16 + 8*hi), Sst);
#pragma unroll
            for (int r = 0; r < 16; ++r) Sst[r] *= blf;
        } else if (wid == 5) {               // P_slow (dual chains)
            f32x16 p1, p2;
#pragma unroll
            for (int r = 0; r < 16; ++r) { p1[r] = 0.0f; p2[r] = 0.0f; }
            const unsigned short* ar = &Qs [i2][l31][0];
            const unsigned short* br = &Ksl[i2][l31][0];
            const int kb = 8*hi;
#pragma unroll
            for (int st = 0; st < 8; st += 2) {
                p1 = MFMA32(ld8(ar + kb + 16*st),     ld8(br + kb + 16*st),     p1);
                p2 = MFMA32(ld8(ar + kb + 16*(st+1)), ld8(br + kb + 16*(st+1)), p2);
            }
#pragma unroll
            for (int r = 0; r < 16; ++r) {
                int tr = CROW(r,hi);
                Psl[i2][tr][l31] = f2b(tr >= l31 ? p1[r] + p2[r] : 0.0f);
            }
        } else if (wid == 6) {               // P_fast
            f32x16 p1;
#pragma unroll
            for (int r = 0; r < 16; ++r) p1[r] = 0.0f;
            const unsigned short* ar = &Qfl[i2][l31][0];
            const unsigned short* br = &Kfl[i2][l31][0];
            p1 = MFMA32(ld8(ar + 8*hi),      ld8(br + 8*hi),      p1);
            p1 = MFMA32(ld8(ar + 16 + 8*hi), ld8(br + 16 + 8*hi), p1);
#pragma unroll
            for (int r = 0; r < 16; ++r) {
                int tr = CROW(r,hi);
                Pfl[i2][tr][l31] = f2b(tr >= l31 ? p1[r] : 0.0f);
            }
        } else {                             // wid 7: y-store(c-1), then inter-out(c)
            if (c > 0) YSTORE(c - 1);
            f32x16 o1, o2;
#pragma unroll
            for (int r = 0; r < 16; ++r) { o1[r] = 0.0f; o2[r] = 0.0f; }
            const unsigned short* ar = &Qs [i2][l31][0];
            const unsigned short* br = &Sbs[i2][l31][0];
            const int kb = 8*hi;
#pragma unroll
            for (int st = 0; st < 8; st += 2) {
                o1 = MFMA32(ld8(ar + kb + 16*st),     ld8(br + kb + 16*st),     o1);
                o2 = MFMA32(ld8(ar + kb + 16*(st+1)), ld8(br + kb + 16*(st+1)), o2);
            }
            const unsigned short* af = &Qfl [i2][l31][0];
            const unsigned short* bf = &Sbfl[i2][l31][0];
            o1 = MFMA32(ld8(af + 8*hi),      ld8(bf + 8*hi),      o1);
            o2 = MFMA32(ld8(af + 16 + 8*hi), ld8(bf + 16 + 8*hi), o2);
#pragma unroll
            for (int r = 0; r < 16; ++r) oacc[r] = o1[r] + o2[r];
        }

        // scan for chunk c+1 (pL* loaded one chunk ago); then depth-2 reload
        SCAN();
        LOADSCL(c + 2);

        // ================= stage phase (chunk c+1) =================
        if (c < NC - 1) {
            const int j2 = (c + 1) & 1;
            const int j3 = (c + 1) % 3;
            if (wid < 4) {
#pragma unroll
                for (int r = 0; r < 16; ++r) Sbs[j2][l31][32*wid + CROW(r,hi)] = f2b(Sst[r]);
            } else if (wid == 4) {
#pragma unroll
                for (int r = 0; r < 16; ++r) Sbfl[j2][l31][CROW(r,hi)] = f2b(Sst[r]);
            }
            STAGE(j2, j3);
        }
        __syncthreads();
    }

    // ---- epilogue: y-store for last chunk, final states ----
    if (wid == 7) {
        YSTORE(NC - 1);
    }
    if (wid < 4) {
#pragma unroll
        for (int r = 0; r < 16; ++r)
            dout[BH*KF_*VF_ + ((size_t)p*KS_ + 32*wid + CROW(r,hi))*VS_ + v0 + l31] = Sst[r];
    } else if (wid == 4) {
#pragma unroll
        for (int r = 0; r < 16; ++r)
            dout[((size_t)p*KF_ + CROW(r,hi))*VF_ + v0 + l31] = Sst[r];
    }
#undef LOADVEC
#undef LOADSCL
#undef SCAN
#undef STAGE
#undef YSTORE
}

extern "C" void kernel_launch(void* const* d_in, const int* in_sizes, int n_in,
                              void* d_out, int out_size, void* d_ws, size_t ws_size,
                              hipStream_t stream)
{
    const float* k_fast     = (const float*)d_in[0];
    const float* v_fast     = (const float*)d_in[1];
    const float* q_fast     = (const float*)d_in[2];
    const float* decay_fast = (const float*)d_in[3];
    const float* k_slow     = (const float*)d_in[4];
    const float* v_slow     = (const float*)d_in[5];
    const float* q_slow     = (const float*)d_in[6];
    const float* decay_slow = (const float*)d_in[7];
    const float* slow_gate  = (const float*)d_in[8];
    const float* mix_fast   = (const float*)d_in[9];
    const float* mix_slow   = (const float*)d_in[10];
    const float* S_fast0    = (const float*)d_in[11];
    const float* S_slow0    = (const float*)d_in[12];
    float* dout = (float*)d_out;

    e90_mfma<<<dim3(256), dim3(NTHR), 0, stream>>>(
        k_fast, v_fast, q_fast, decay_fast,
        k_slow, v_slow, q_slow, decay_slow,
        slow_gate, mix_fast, mix_slow, S_fast0, S_slow0, dout);
}